// Round 1
// 613.770 us; speedup vs baseline: 1.0962x; 1.0962x over previous
//
#include <hip/hip_runtime.h>
#include <cstdint>
#include <cstddef>

#define NH 8
#define NB 4
#define SS 2048
#define FF 64
#define DD 8
#define QKV_SZ (NH*NB*SS*DD)   // 524288 floats = 2 MB

// Full 64-lane sum via DPP (rocPRIM sequence). Result valid in lane 63.
__device__ __forceinline__ float wave_sum64(float x) {
#define DPP_STEP(ctrl, rm) { int t_ = __builtin_amdgcn_update_dpp(0, __float_as_int(x), (ctrl), (rm), 0xf, true); x += __int_as_float(t_); }
  DPP_STEP(0x111, 0xf)  // row_shr:1
  DPP_STEP(0x112, 0xf)  // row_shr:2
  DPP_STEP(0x114, 0xf)  // row_shr:4
  DPP_STEP(0x118, 0xf)  // row_shr:8
  DPP_STEP(0x142, 0xa)  // row_bcast:15 -> rows 1,3
  DPP_STEP(0x143, 0xc)  // row_bcast:31 -> rows 2,3
#undef DPP_STEP
  return x;
}

// ---------------- Kernel A: QKV projection ----------------
// Q is pre-scaled by 1/sqrt(8). Layouts: Q/K/V = [h][b][s][d].
// grid (128, 2): by splits the 192 outputs in half -> 256 blocks fill all CUs.
__global__ __launch_bounds__(256) void qkv_kernel(
    const float* __restrict__ x,
    const float* __restrict__ Wq, const float* __restrict__ Wk, const float* __restrict__ Wv,
    float* __restrict__ Qo, float* __restrict__ Ko, float* __restrict__ Vo) {
  __shared__ float xT[64][65];  // pad 65: staging writes 2-way (free), reads 2-way broadcast
  const int tid = threadIdx.x;
  const int row0 = blockIdx.x * 64;
  // stage 64 rows of x, transposed
  #pragma unroll
  for (int k = 0; k < 4; ++k) {
    int flat4 = tid + 256 * k;          // 0..1023
    int r = flat4 >> 4, fq = flat4 & 15;
    float4 xv = reinterpret_cast<const float4*>(x)[(size_t)(row0 + r) * 16 + fq];
    xT[fq * 4 + 0][r] = xv.x; xT[fq * 4 + 1][r] = xv.y;
    xT[fq * 4 + 2][r] = xv.z; xT[fq * 4 + 3][r] = xv.w;
  }
  __syncthreads();
  const int r = tid & 63;
  const int g = __builtin_amdgcn_readfirstlane(tid >> 6);  // wave-uniform output group
  const int obase = g * 24 + blockIdx.y * 96;
  float acc[24];
  #pragma unroll
  for (int i = 0; i < 24; ++i) acc[i] = 0.f;
  for (int f = 0; f < 64; ++f) {
    float xv = xT[f][r];
    #pragma unroll
    for (int i = 0; i < 24; ++i) {
      int o = obase + i;
      const float* Wsel = (o < 64) ? Wq : ((o < 128) ? Wk : Wv);
      int oc = o & 63;
      // W[h][f][d] flat = h*512 + f*8 + d
      acc[i] = fmaf(xv, Wsel[((oc >> 3) << 9) + f * 8 + (oc & 7)], acc[i]);
    }
  }
  const int row = row0 + r;
  const int b = row >> 11, s = row & 2047;
  const float qscale = 0.35355339059327373f;  // 1/sqrt(8)
  #pragma unroll
  for (int i = 0; i < 24; ++i) {
    int o = obase + i;
    int m = o >> 6, oc = o & 63, h = oc >> 3, d = oc & 7;
    float v = acc[i];
    if (m == 0) v *= qscale;
    float* dst = (m == 0) ? Qo : ((m == 1) ? Ko : Vo);
    dst[(((size_t)(h * NB + b) * SS) + s) * DD + d] = v;
  }
}

// ---------------- Kernel B: softmax weights + head sums ----------------
// Grid: 1024 blocks = 32 (h,b) x 32 row-tiles of 64 rows. 256 threads = 4 waves.
// Phase 1 (lane = row): per-wave-private LDS K chunks, broadcast k_t reads,
//   per-lane running rowsum -> no DPP chains, no per-row global Q loads.
// Phase 2 (lane = t-pair): normalized weights written as float2 + per-t column
//   sums; V applied once per chunk (colsum trick: sum_r heads = sum_t colsum*V).
__global__ __launch_bounds__(256, 4) void attn_kernel(
    const float* __restrict__ Qg, const float* __restrict__ Kg, const float* __restrict__ Vg,
    float* __restrict__ wOut, float* __restrict__ hsum2) {
  __shared__ float4 klds[4 * 512];   // 4 waves x 256 t x 2 float4 = 32 KB (wave-private)
  __shared__ float4 qlds[128];       // 64 rows x 8 floats = 2 KB (for phase 2)
  __shared__ float psum[4][64];
  __shared__ float rinv_s[64];
  __shared__ float hred[4][8];
  const int tid = threadIdx.x;
  const int lane = tid & 63;
  const int w = tid >> 6;
  const int bx = blockIdx.x;
  const int hb = bx >> 5;   // h*4+b
  const int rt = bx & 31;
  const int r0 = rt * 64;
  const float* Kbase = Kg + (size_t)hb * SS * DD;
  const float* Vbase = Vg + (size_t)hb * SS * DD;
  const float4* K4 = reinterpret_cast<const float4*>(Kbase);
  const float4* Q4 = reinterpret_cast<const float4*>(Qg + (size_t)hb * SS * DD + (size_t)r0 * DD);
  float* wBase = wOut + (size_t)hb * SS * SS + (size_t)r0 * SS;

  // stage Q tile for phase 2 (consumed after the psum barrier)
  if (tid < 128) qlds[tid] = Q4[tid];

  // ---- Phase 1: row sums. lane = row r0+lane; wave w covers t in [w*512, w*512+512). ----
  float4 qa = Q4[lane * 2], qb = Q4[lane * 2 + 1];
  const float q0 = qa.x, q1 = qa.y, q2 = qa.z, q3 = qa.w;
  const float q4_ = qb.x, q5 = qb.y, q6 = qb.z, q7 = qb.w;
  float rs0 = 0.f, rs1 = 0.f;
  float4* kw = klds + w * 512;   // this wave's private 8 KB buffer
  for (int cc = 0; cc < 2; ++cc) {
    const int t0 = (w * 2 + cc) * 256;
    // stage 256 K rows (8 KB) cooperatively within the wave; no block barrier needed
    #pragma unroll
    for (int i = 0; i < 8; ++i) kw[lane + 64 * i] = K4[(size_t)t0 * 2 + lane + 64 * i];
    // broadcast reads with depth-1 register prefetch (2 t per step)
    float4 a0 = kw[0], b0 = kw[1], a1 = kw[2], b1 = kw[3];
    #pragma unroll 2
    for (int tt = 0; tt < 256; tt += 2) {
      const int tn = (tt + 2 < 256) ? (tt + 2) : 254;
      float4 na0 = kw[2 * tn], nb0 = kw[2 * tn + 1];
      float4 na1 = kw[2 * tn + 2], nb1 = kw[2 * tn + 3];
      float s0 = q0 * a0.x;
      s0 = fmaf(q1, a0.y, s0); s0 = fmaf(q2, a0.z, s0); s0 = fmaf(q3, a0.w, s0);
      s0 = fmaf(q4_, b0.x, s0); s0 = fmaf(q5, b0.y, s0); s0 = fmaf(q6, b0.z, s0);
      s0 = fmaf(q7, b0.w, s0);
      float s1 = q0 * a1.x;
      s1 = fmaf(q1, a1.y, s1); s1 = fmaf(q2, a1.z, s1); s1 = fmaf(q3, a1.w, s1);
      s1 = fmaf(q4_, b1.x, s1); s1 = fmaf(q5, b1.y, s1); s1 = fmaf(q6, b1.z, s1);
      s1 = fmaf(q7, b1.w, s1);
      rs0 += __expf(s0);
      rs1 += __expf(s1);
      a0 = na0; b0 = nb0; a1 = na1; b1 = nb1;
    }
  }
  psum[w][lane] = rs0 + rs1;
  __syncthreads();
  if (tid < 64)
    rinv_s[tid] = 1.0f / (psum[0][tid] + psum[1][tid] + psum[2][tid] + psum[3][tid]);
  __syncthreads();

  // ---- Phase 2: write weights + column sums. lane owns t = tbase+2*lane, +1. ----
  float A[8] = {0.f, 0.f, 0.f, 0.f, 0.f, 0.f, 0.f, 0.f};
  for (int ci = 0; ci < 4; ++ci) {
    const int c = w * 4 + ci;          // 0..15
    const int tbase = c * 128;
    const float4* kp = reinterpret_cast<const float4*>(Kbase + (size_t)(tbase + 2 * lane) * DD);
    float4 k0a = kp[0], k0b = kp[1], k1a = kp[2], k1b = kp[3];
    float4 qa2 = qlds[0], qb2 = qlds[1];
    float cs0 = 0.f, cs1 = 0.f;
    for (int r = 0; r < 64; ++r) {
      const int rn = (r < 63) ? (r + 1) : 63;
      float4 na = qlds[rn * 2], nb = qlds[rn * 2 + 1];  // prefetch next row's q (LDS broadcast)
      const float rin = rinv_s[r];
      float s0 = qa2.x * k0a.x;
      s0 = fmaf(qa2.y, k0a.y, s0); s0 = fmaf(qa2.z, k0a.z, s0); s0 = fmaf(qa2.w, k0a.w, s0);
      s0 = fmaf(qb2.x, k0b.x, s0); s0 = fmaf(qb2.y, k0b.y, s0); s0 = fmaf(qb2.z, k0b.z, s0);
      s0 = fmaf(qb2.w, k0b.w, s0);
      float s1 = qa2.x * k1a.x;
      s1 = fmaf(qa2.y, k1a.y, s1); s1 = fmaf(qa2.z, k1a.z, s1); s1 = fmaf(qa2.w, k1a.w, s1);
      s1 = fmaf(qb2.x, k1b.x, s1); s1 = fmaf(qb2.y, k1b.y, s1); s1 = fmaf(qb2.z, k1b.z, s1);
      s1 = fmaf(qb2.w, k1b.w, s1);
      float p0 = __expf(s0) * rin;
      float p1 = __expf(s1) * rin;
      reinterpret_cast<float2*>(wBase + (size_t)r * SS + tbase)[lane] = make_float2(p0, p1);
      cs0 += p0; cs1 += p1;
      qa2 = na; qb2 = nb;
    }
    // apply V once per chunk: A[d] += colsum(t) * V[t][d]
    const float4* vp = reinterpret_cast<const float4*>(Vbase + (size_t)(tbase + 2 * lane) * DD);
    float4 v0a = vp[0], v0b = vp[1], v1a = vp[2], v1b = vp[3];
    A[0] = fmaf(cs0, v0a.x, A[0]); A[0] = fmaf(cs1, v1a.x, A[0]);
    A[1] = fmaf(cs0, v0a.y, A[1]); A[1] = fmaf(cs1, v1a.y, A[1]);
    A[2] = fmaf(cs0, v0a.z, A[2]); A[2] = fmaf(cs1, v1a.z, A[2]);
    A[3] = fmaf(cs0, v0a.w, A[3]); A[3] = fmaf(cs1, v1a.w, A[3]);
    A[4] = fmaf(cs0, v0b.x, A[4]); A[4] = fmaf(cs1, v1b.x, A[4]);
    A[5] = fmaf(cs0, v0b.y, A[5]); A[5] = fmaf(cs1, v1b.y, A[5]);
    A[6] = fmaf(cs0, v0b.z, A[6]); A[6] = fmaf(cs1, v1b.z, A[6]);
    A[7] = fmaf(cs0, v0b.w, A[7]); A[7] = fmaf(cs1, v1b.w, A[7]);
  }

  // block-level reduce of A[d] -> hsum2[bx][d]
  #pragma unroll
  for (int d = 0; d < 8; ++d) {
    float t = wave_sum64(A[d]);
    if (lane == 63) hred[w][d] = t;
  }
  __syncthreads();
  if (tid < 8) {
    float t = hred[0][tid] + hred[1][tid] + hred[2][tid] + hred[3][tid];
    hsum2[(size_t)bx * 8 + tid] = t;
  }
}

// ---------------- Kernel C: combine head sums + output projection ----------------
__global__ __launch_bounds__(256) void out_kernel(
    const float* __restrict__ hsum2, const float* __restrict__ Wo,
    float* __restrict__ out) {
  __shared__ float ch[256];  // [hb][d] = [h*4+b]*8 + d
  const int tid = threadIdx.x;
  {
    int hb = tid >> 3, d = tid & 7;
    float s = 0.f;
    for (int rtile = 0; rtile < 32; ++rtile) s += hsum2[(size_t)(hb * 32 + rtile) * 8 + d];
    ch[tid] = s;
  }
  __syncthreads();
  const int b = tid >> 6, f = tid & 63;
  float acc = 0.f;
  for (int h = 0; h < 8; ++h) {
    #pragma unroll
    for (int d = 0; d < 8; ++d) {
      // concat[b][h*8+d] @ Wo[h*8+d][f]
      acc = fmaf(ch[(h * 4 + b) * 8 + d], Wo[(h * 8 + d) * 64 + f], acc);
    }
  }
  out[b * 64 + f] = acc;
}

extern "C" void kernel_launch(void* const* d_in, const int* in_sizes, int n_in,
                              void* d_out, int out_size, void* d_ws, size_t ws_size,
                              hipStream_t stream) {
  const float* x  = (const float*)d_in[0];
  const float* Wq = (const float*)d_in[1];
  const float* Wk = (const float*)d_in[2];
  const float* Wv = (const float*)d_in[3];
  const float* Wo = (const float*)d_in[4];
  float* out = (float*)d_out;           // [4,64] = 256 floats
  float* wts = out + 256;               // weights [8,4,2048,2048]
  float* ws = (float*)d_ws;
  float* Q = ws;
  float* K = ws + QKV_SZ;
  float* V = ws + 2 * (size_t)QKV_SZ;
  float* hs = ws + 3 * (size_t)QKV_SZ;  // [1024][8]

  qkv_kernel<<<dim3(128, 2), 256, 0, stream>>>(x, Wq, Wk, Wv, Q, K, V);
  attn_kernel<<<1024, 256, 0, stream>>>(Q, K, V, wts, hs);
  out_kernel<<<1, 256, 0, stream>>>(hs, Wo, out);
}

// Round 3
// 582.493 us; speedup vs baseline: 1.1551x; 1.0537x over previous
//
#include <hip/hip_runtime.h>
#include <cstdint>
#include <cstddef>

#define NH 8
#define NB 4
#define SS 2048
#define FF 64
#define DD 8
#define QKV_SZ (NH*NB*SS*DD)   // 524288 floats = 2 MB

// Full 64-lane sum via DPP (rocPRIM sequence). Result valid in lane 63.
__device__ __forceinline__ float wave_sum64(float x) {
#define DPP_STEP(ctrl, rm) { int t_ = __builtin_amdgcn_update_dpp(0, __float_as_int(x), (ctrl), (rm), 0xf, true); x += __int_as_float(t_); }
  DPP_STEP(0x111, 0xf)  // row_shr:1
  DPP_STEP(0x112, 0xf)  // row_shr:2
  DPP_STEP(0x114, 0xf)  // row_shr:4
  DPP_STEP(0x118, 0xf)  // row_shr:8
  DPP_STEP(0x142, 0xa)  // row_bcast:15 -> rows 1,3
  DPP_STEP(0x143, 0xc)  // row_bcast:31 -> rows 2,3
#undef DPP_STEP
  return x;
}

// ---------------- Kernel A: QKV projection ----------------
// Q is pre-scaled by 1/sqrt(8). Layouts: Q/K/V = [h][b][s][d].
// Wave-group wg (0..7) owns 3 (m,h) combos, producing all 8 d each ->
// fully-coalesced float4 stores and wave-uniform (scalar) weight reads.
__global__ __launch_bounds__(256) void qkv_kernel(
    const float* __restrict__ x,
    const float* __restrict__ Wq, const float* __restrict__ Wk, const float* __restrict__ Wv,
    float* __restrict__ Qo, float* __restrict__ Ko, float* __restrict__ Vo) {
  __shared__ float xT[64][65];  // pad 65: conflict-free
  const int tid = threadIdx.x;
  const int row0 = blockIdx.x * 64;
  // stage 64 rows of x, transposed
  #pragma unroll
  for (int k = 0; k < 4; ++k) {
    int flat4 = tid + 256 * k;          // 0..1023
    int r = flat4 >> 4, fq = flat4 & 15;
    float4 xv = reinterpret_cast<const float4*>(x)[(size_t)(row0 + r) * 16 + fq];
    xT[fq * 4 + 0][r] = xv.x; xT[fq * 4 + 1][r] = xv.y;
    xT[fq * 4 + 2][r] = xv.z; xT[fq * 4 + 3][r] = xv.w;
  }
  __syncthreads();
  const int r = tid & 63;
  const int wg = __builtin_amdgcn_readfirstlane((int)(blockIdx.y * 4 + (tid >> 6)));  // 0..7
  const float* Wmh[3];
  #pragma unroll
  for (int j = 0; j < 3; ++j) {
    int c = wg * 3 + j;                 // 0..23 = m*8 + h
    int m = c >> 3, h = c & 7;
    const float* Wsel = (m == 0) ? Wq : ((m == 1) ? Wk : Wv);
    Wmh[j] = Wsel + (h << 9);           // W[h][f][d] flat = h*512 + f*8 + d
  }
  float acc[3][8];
  #pragma unroll
  for (int j = 0; j < 3; ++j)
    #pragma unroll
    for (int d = 0; d < 8; ++d) acc[j][d] = 0.f;
  for (int f = 0; f < 64; ++f) {
    float xv = xT[f][r];
    #pragma unroll
    for (int j = 0; j < 3; ++j) {
      const float4* wp = reinterpret_cast<const float4*>(Wmh[j] + f * 8);
      float4 wa = wp[0], wb = wp[1];    // wave-uniform -> scalar loads
      acc[j][0] = fmaf(xv, wa.x, acc[j][0]); acc[j][1] = fmaf(xv, wa.y, acc[j][1]);
      acc[j][2] = fmaf(xv, wa.z, acc[j][2]); acc[j][3] = fmaf(xv, wa.w, acc[j][3]);
      acc[j][4] = fmaf(xv, wb.x, acc[j][4]); acc[j][5] = fmaf(xv, wb.y, acc[j][5]);
      acc[j][6] = fmaf(xv, wb.z, acc[j][6]); acc[j][7] = fmaf(xv, wb.w, acc[j][7]);
    }
  }
  const int row = row0 + r;
  const int b = row >> 11, s = row & 2047;
  const float qscale = 0.35355339059327373f;  // 1/sqrt(8)
  #pragma unroll
  for (int j = 0; j < 3; ++j) {
    int c = wg * 3 + j;
    int m = c >> 3, h = c & 7;
    float sc = (m == 0) ? qscale : 1.f;
    float* dst = ((m == 0) ? Qo : ((m == 1) ? Ko : Vo)) + (((size_t)(h * NB + b) * SS) + s) * DD;
    float4 o0 = make_float4(acc[j][0] * sc, acc[j][1] * sc, acc[j][2] * sc, acc[j][3] * sc);
    float4 o1 = make_float4(acc[j][4] * sc, acc[j][5] * sc, acc[j][6] * sc, acc[j][7] * sc);
    reinterpret_cast<float4*>(dst)[0] = o0;
    reinterpret_cast<float4*>(dst)[1] = o1;
  }
}

// ---------------- Kernel B: softmax weights + head sums ----------------
// Grid: 1024 blocks = 32 (h,b) x 32 row-tiles of 64 rows. 256 threads = 4 waves.
// Phase 1 (lane = row): per-wave-private LDS K chunks, broadcast k_t reads,
//   per-lane running rowsum, 4 t per step with register prefetch.
// Phase 2 (lane = 4 t): normalization folded into FMA seed (nls = -log rowsum),
//   float4 weight stores, colsum trick for the head sums.
__global__ __launch_bounds__(256, 4) void attn_kernel(
    const float* __restrict__ Qg, const float* __restrict__ Kg, const float* __restrict__ Vg,
    float* __restrict__ wOut, float* __restrict__ hsum2) {
  __shared__ float4 klds[4 * 512];   // 4 waves x 256 t x 2 float4 = 32 KB (wave-private)
  __shared__ float4 qlds[128];       // 64 rows x 8 floats = 2 KB (for phase 2)
  __shared__ float psum[4][64];
  __shared__ float nls_s[64];        // -log(rowsum)
  __shared__ float hred[4][8];
  const int tid = threadIdx.x;
  const int lane = tid & 63;
  const int w = tid >> 6;
  const int bx = blockIdx.x;
  const int hb = bx >> 5;   // h*4+b
  const int rt = bx & 31;
  const int r0 = rt * 64;
  const float* Kbase = Kg + (size_t)hb * SS * DD;
  const float* Vbase = Vg + (size_t)hb * SS * DD;
  const float4* K4 = reinterpret_cast<const float4*>(Kbase);
  const float4* Q4 = reinterpret_cast<const float4*>(Qg + (size_t)hb * SS * DD + (size_t)r0 * DD);
  float* wBase = wOut + (size_t)hb * SS * SS + (size_t)r0 * SS;

  // stage Q tile for phase 2 (consumed after the psum barrier)
  if (tid < 128) qlds[tid] = Q4[tid];

  // ---- Phase 1: row sums. lane = row r0+lane; wave w covers t in [w*512, w*512+512). ----
  float4 qa = Q4[lane * 2], qb = Q4[lane * 2 + 1];
  const float q0 = qa.x, q1 = qa.y, q2 = qa.z, q3 = qa.w;
  const float q4_ = qb.x, q5 = qb.y, q6 = qb.z, q7 = qb.w;
  float rs0 = 0.f, rs1 = 0.f;
  float4* kw = klds + w * 512;   // this wave's private 8 KB buffer
  for (int cc = 0; cc < 2; ++cc) {
    const int t0 = (w * 2 + cc) * 256;
    // stage 256 K rows (8 KB) cooperatively within the wave; no block barrier needed
    #pragma unroll
    for (int i = 0; i < 8; ++i) kw[lane + 64 * i] = K4[(size_t)t0 * 2 + lane + 64 * i];
    // broadcast reads with register prefetch (4 t per step)
    float4 a0 = kw[0], b0 = kw[1], a1 = kw[2], b1 = kw[3];
    float4 a2 = kw[4], b2 = kw[5], a3 = kw[6], b3 = kw[7];
    for (int tt = 0; tt < 256; tt += 4) {
      const int tn = (tt + 4 < 256) ? (tt + 4) : 0;  // wrap = dummy prefetch
      float4 na0 = kw[2 * tn],     nb0 = kw[2 * tn + 1];
      float4 na1 = kw[2 * tn + 2], nb1 = kw[2 * tn + 3];
      float4 na2 = kw[2 * tn + 4], nb2 = kw[2 * tn + 5];
      float4 na3 = kw[2 * tn + 6], nb3 = kw[2 * tn + 7];
      float s0 = q0 * a0.x;
      s0 = fmaf(q1, a0.y, s0); s0 = fmaf(q2, a0.z, s0); s0 = fmaf(q3, a0.w, s0);
      s0 = fmaf(q4_, b0.x, s0); s0 = fmaf(q5, b0.y, s0); s0 = fmaf(q6, b0.z, s0);
      s0 = fmaf(q7, b0.w, s0);
      float s1 = q0 * a1.x;
      s1 = fmaf(q1, a1.y, s1); s1 = fmaf(q2, a1.z, s1); s1 = fmaf(q3, a1.w, s1);
      s1 = fmaf(q4_, b1.x, s1); s1 = fmaf(q5, b1.y, s1); s1 = fmaf(q6, b1.z, s1);
      s1 = fmaf(q7, b1.w, s1);
      float s2 = q0 * a2.x;
      s2 = fmaf(q1, a2.y, s2); s2 = fmaf(q2, a2.z, s2); s2 = fmaf(q3, a2.w, s2);
      s2 = fmaf(q4_, b2.x, s2); s2 = fmaf(q5, b2.y, s2); s2 = fmaf(q6, b2.z, s2);
      s2 = fmaf(q7, b2.w, s2);
      float s3 = q0 * a3.x;
      s3 = fmaf(q1, a3.y, s3); s3 = fmaf(q2, a3.z, s3); s3 = fmaf(q3, a3.w, s3);
      s3 = fmaf(q4_, b3.x, s3); s3 = fmaf(q5, b3.y, s3); s3 = fmaf(q6, b3.z, s3);
      s3 = fmaf(q7, b3.w, s3);
      rs0 += __expf(s0) + __expf(s1);
      rs1 += __expf(s2) + __expf(s3);
      a0 = na0; b0 = nb0; a1 = na1; b1 = nb1;
      a2 = na2; b2 = nb2; a3 = na3; b3 = nb3;
    }
  }
  psum[w][lane] = rs0 + rs1;
  __syncthreads();
  if (tid < 64)
    nls_s[tid] = -__logf(psum[0][tid] + psum[1][tid] + psum[2][tid] + psum[3][tid]);
  __syncthreads();

  // ---- Phase 2: lane owns t = tbase + 4*lane + {0..3}; float4 weight stores. ----
  float A[8] = {0.f, 0.f, 0.f, 0.f, 0.f, 0.f, 0.f, 0.f};
  for (int ci = 0; ci < 2; ++ci) {
    const int c = w * 2 + ci;          // 0..7
    const int tbase = c * 256;
    const int tl = tbase + 4 * lane;   // first t for this lane
    const float4* kp = reinterpret_cast<const float4*>(Kbase + (size_t)tl * DD);
    float4 k0a = kp[0], k0b = kp[1], k1a = kp[2], k1b = kp[3];
    float4 k2a = kp[4], k2b = kp[5], k3a = kp[6], k3b = kp[7];
    float4 qa2 = qlds[0], qb2 = qlds[1];
    float cs0 = 0.f, cs1 = 0.f, cs2 = 0.f, cs3 = 0.f;
    for (int r = 0; r < 64; ++r) {
      const int rn = (r < 63) ? (r + 1) : 63;
      float4 na = qlds[rn * 2], nb = qlds[rn * 2 + 1];  // prefetch next row's q
      const float nl = nls_s[r];
      float s0 = fmaf(qa2.x, k0a.x, nl);
      s0 = fmaf(qa2.y, k0a.y, s0); s0 = fmaf(qa2.z, k0a.z, s0); s0 = fmaf(qa2.w, k0a.w, s0);
      s0 = fmaf(qb2.x, k0b.x, s0); s0 = fmaf(qb2.y, k0b.y, s0); s0 = fmaf(qb2.z, k0b.z, s0);
      s0 = fmaf(qb2.w, k0b.w, s0);
      float s1 = fmaf(qa2.x, k1a.x, nl);
      s1 = fmaf(qa2.y, k1a.y, s1); s1 = fmaf(qa2.z, k1a.z, s1); s1 = fmaf(qa2.w, k1a.w, s1);
      s1 = fmaf(qb2.x, k1b.x, s1); s1 = fmaf(qb2.y, k1b.y, s1); s1 = fmaf(qb2.z, k1b.z, s1);
      s1 = fmaf(qb2.w, k1b.w, s1);
      float s2 = fmaf(qa2.x, k2a.x, nl);
      s2 = fmaf(qa2.y, k2a.y, s2); s2 = fmaf(qa2.z, k2a.z, s2); s2 = fmaf(qa2.w, k2a.w, s2);
      s2 = fmaf(qb2.x, k2b.x, s2); s2 = fmaf(qb2.y, k2b.y, s2); s2 = fmaf(qb2.z, k2b.z, s2);
      s2 = fmaf(qb2.w, k2b.w, s2);
      float s3 = fmaf(qa2.x, k3a.x, nl);
      s3 = fmaf(qa2.y, k3a.y, s3); s3 = fmaf(qa2.z, k3a.z, s3); s3 = fmaf(qa2.w, k3a.w, s3);
      s3 = fmaf(qb2.x, k3b.x, s3); s3 = fmaf(qb2.y, k3b.y, s3); s3 = fmaf(qb2.z, k3b.z, s3);
      s3 = fmaf(qb2.w, k3b.w, s3);
      float p0 = __expf(s0), p1 = __expf(s1), p2 = __expf(s2), p3 = __expf(s3);
      reinterpret_cast<float4*>(wBase + (size_t)r * SS + tl)[0] = make_float4(p0, p1, p2, p3);
      cs0 += p0; cs1 += p1; cs2 += p2; cs3 += p3;
      qa2 = na; qb2 = nb;
    }
    // apply V once per chunk: A[d] += colsum(t) * V[t][d]
    const float4* vp = reinterpret_cast<const float4*>(Vbase + (size_t)tl * DD);
    float4 v0a = vp[0], v0b = vp[1], v1a = vp[2], v1b = vp[3];
    float4 v2a = vp[4], v2b = vp[5], v3a = vp[6], v3b = vp[7];
    A[0] = fmaf(cs0, v0a.x, A[0]); A[0] = fmaf(cs1, v1a.x, A[0]);
    A[0] = fmaf(cs2, v2a.x, A[0]); A[0] = fmaf(cs3, v3a.x, A[0]);
    A[1] = fmaf(cs0, v0a.y, A[1]); A[1] = fmaf(cs1, v1a.y, A[1]);
    A[1] = fmaf(cs2, v2a.y, A[1]); A[1] = fmaf(cs3, v3a.y, A[1]);
    A[2] = fmaf(cs0, v0a.z, A[2]); A[2] = fmaf(cs1, v1a.z, A[2]);
    A[2] = fmaf(cs2, v2a.z, A[2]); A[2] = fmaf(cs3, v3a.z, A[2]);
    A[3] = fmaf(cs0, v0a.w, A[3]); A[3] = fmaf(cs1, v1a.w, A[3]);
    A[3] = fmaf(cs2, v2a.w, A[3]); A[3] = fmaf(cs3, v3a.w, A[3]);
    A[4] = fmaf(cs0, v0b.x, A[4]); A[4] = fmaf(cs1, v1b.x, A[4]);
    A[4] = fmaf(cs2, v2b.x, A[4]); A[4] = fmaf(cs3, v3b.x, A[4]);
    A[5] = fmaf(cs0, v0b.y, A[5]); A[5] = fmaf(cs1, v1b.y, A[5]);
    A[5] = fmaf(cs2, v2b.y, A[5]); A[5] = fmaf(cs3, v3b.y, A[5]);
    A[6] = fmaf(cs0, v0b.z, A[6]); A[6] = fmaf(cs1, v1b.z, A[6]);
    A[6] = fmaf(cs2, v2b.z, A[6]); A[6] = fmaf(cs3, v3b.z, A[6]);
    A[7] = fmaf(cs0, v0b.w, A[7]); A[7] = fmaf(cs1, v1b.w, A[7]);
    A[7] = fmaf(cs2, v2b.w, A[7]); A[7] = fmaf(cs3, v3b.w, A[7]);
  }

  // block-level reduce of A[d] -> hsum2[bx][d]
  #pragma unroll
  for (int d = 0; d < 8; ++d) {
    float t = wave_sum64(A[d]);
    if (lane == 63) hred[w][d] = t;
  }
  __syncthreads();
  if (tid < 8) {
    float t = hred[0][tid] + hred[1][tid] + hred[2][tid] + hred[3][tid];
    hsum2[(size_t)bx * 8 + tid] = t;
  }
}

// ---------------- Kernel C: combine head sums + output projection ----------------
__global__ __launch_bounds__(256) void out_kernel(
    const float* __restrict__ hsum2, const float* __restrict__ Wo,
    float* __restrict__ out) {
  __shared__ float ch[256];  // [hb][d] = [h*4+b]*8 + d
  const int tid = threadIdx.x;
  {
    int hb = tid >> 3, d = tid & 7;
    float s = 0.f;
    for (int rtile = 0; rtile < 32; ++rtile) s += hsum2[(size_t)(hb * 32 + rtile) * 8 + d];
    ch[tid] = s;
  }
  __syncthreads();
  const int b = tid >> 6, f = tid & 63;
  float acc = 0.f;
  for (int h = 0; h < 8; ++h) {
    #pragma unroll
    for (int d = 0; d < 8; ++d) {
      // concat[b][h*8+d] @ Wo[h*8+d][f]
      acc = fmaf(ch[(h * 4 + b) * 8 + d], Wo[(h * 8 + d) * 64 + f], acc);
    }
  }
  out[b * 64 + f] = acc;
}

extern "C" void kernel_launch(void* const* d_in, const int* in_sizes, int n_in,
                              void* d_out, int out_size, void* d_ws, size_t ws_size,
                              hipStream_t stream) {
  const float* x  = (const float*)d_in[0];
  const float* Wq = (const float*)d_in[1];
  const float* Wk = (const float*)d_in[2];
  const float* Wv = (const float*)d_in[3];
  const float* Wo = (const float*)d_in[4];
  float* out = (float*)d_out;           // [4,64] = 256 floats
  float* wts = out + 256;               // weights [8,4,2048,2048]
  float* ws = (float*)d_ws;
  float* Q = ws;
  float* K = ws + QKV_SZ;
  float* V = ws + 2 * (size_t)QKV_SZ;
  float* hs = ws + 3 * (size_t)QKV_SZ;  // [1024][8]

  qkv_kernel<<<dim3(128, 2), 256, 0, stream>>>(x, Wq, Wk, Wv, Q, K, V);
  attn_kernel<<<1024, 256, 0, stream>>>(Q, K, V, wts, hs);
  out_kernel<<<1, 256, 0, stream>>>(hs, Wo, out);
}

// Round 4
// 575.594 us; speedup vs baseline: 1.1689x; 1.0120x over previous
//
#include <hip/hip_runtime.h>
#include <cstdint>
#include <cstddef>

#define NH 8
#define NB 4
#define SS 2048
#define FF 64
#define DD 8
#define QKV_SZ (NH*NB*SS*DD)   // 524288 floats = 2 MB

typedef float f32x2 __attribute__((ext_vector_type(2)));

__device__ __forceinline__ f32x2 pkfma(f32x2 a, f32x2 b, f32x2 c) {
#if __has_builtin(__builtin_elementwise_fma)
  return __builtin_elementwise_fma(a, b, c);   // -> v_pk_fma_f32 on CDNA
#else
  f32x2 r; r.x = fmaf(a.x, b.x, c.x); r.y = fmaf(a.y, b.y, c.y); return r;
#endif
}

__device__ __forceinline__ float fastexp2(float x) {
#if __has_builtin(__builtin_amdgcn_exp2f)
  return __builtin_amdgcn_exp2f(x);            // raw v_exp_f32
#else
  return exp2f(x);
#endif
}

__device__ __forceinline__ f32x2 lo2(float4 v) { f32x2 r; r.x = v.x; r.y = v.y; return r; }
__device__ __forceinline__ f32x2 hi2(float4 v) { f32x2 r; r.x = v.z; r.y = v.w; return r; }

// Full 64-lane sum via DPP (rocPRIM sequence). Result valid in lane 63.
__device__ __forceinline__ float wave_sum64(float x) {
#define DPP_STEP(ctrl, rm) { int t_ = __builtin_amdgcn_update_dpp(0, __float_as_int(x), (ctrl), (rm), 0xf, true); x += __int_as_float(t_); }
  DPP_STEP(0x111, 0xf)  // row_shr:1
  DPP_STEP(0x112, 0xf)  // row_shr:2
  DPP_STEP(0x114, 0xf)  // row_shr:4
  DPP_STEP(0x118, 0xf)  // row_shr:8
  DPP_STEP(0x142, 0xa)  // row_bcast:15 -> rows 1,3
  DPP_STEP(0x143, 0xc)  // row_bcast:31 -> rows 2,3
#undef DPP_STEP
  return x;
}

// ---------------- Kernel A: QKV projection ----------------
// Q is pre-scaled by log2(e)/sqrt(8) so attention works in exp2 domain.
// Layouts: Q/K/V = [h][b][s][d]. Wave-group wg (0..7) owns 3 (m,h) combos ->
// fully-coalesced float4 stores and wave-uniform (scalar) weight reads.
__global__ __launch_bounds__(256) void qkv_kernel(
    const float* __restrict__ x,
    const float* __restrict__ Wq, const float* __restrict__ Wk, const float* __restrict__ Wv,
    float* __restrict__ Qo, float* __restrict__ Ko, float* __restrict__ Vo) {
  __shared__ float xT[64][65];  // pad 65: conflict-free
  const int tid = threadIdx.x;
  const int row0 = blockIdx.x * 64;
  // stage 64 rows of x, transposed
  #pragma unroll
  for (int k = 0; k < 4; ++k) {
    int flat4 = tid + 256 * k;          // 0..1023
    int r = flat4 >> 4, fq = flat4 & 15;
    float4 xv = reinterpret_cast<const float4*>(x)[(size_t)(row0 + r) * 16 + fq];
    xT[fq * 4 + 0][r] = xv.x; xT[fq * 4 + 1][r] = xv.y;
    xT[fq * 4 + 2][r] = xv.z; xT[fq * 4 + 3][r] = xv.w;
  }
  __syncthreads();
  const int r = tid & 63;
  const int wg = __builtin_amdgcn_readfirstlane((int)(blockIdx.y * 4 + (tid >> 6)));  // 0..7
  const float* Wmh[3];
  #pragma unroll
  for (int j = 0; j < 3; ++j) {
    int c = wg * 3 + j;                 // 0..23 = m*8 + h
    int m = c >> 3, h = c & 7;
    const float* Wsel = (m == 0) ? Wq : ((m == 1) ? Wk : Wv);
    Wmh[j] = Wsel + (h << 9);           // W[h][f][d] flat = h*512 + f*8 + d
  }
  float acc[3][8];
  #pragma unroll
  for (int j = 0; j < 3; ++j)
    #pragma unroll
    for (int d = 0; d < 8; ++d) acc[j][d] = 0.f;
  for (int f = 0; f < 64; ++f) {
    float xv = xT[f][r];
    #pragma unroll
    for (int j = 0; j < 3; ++j) {
      const float4* wp = reinterpret_cast<const float4*>(Wmh[j] + f * 8);
      float4 wa = wp[0], wb = wp[1];    // wave-uniform -> scalar loads
      acc[j][0] = fmaf(xv, wa.x, acc[j][0]); acc[j][1] = fmaf(xv, wa.y, acc[j][1]);
      acc[j][2] = fmaf(xv, wa.z, acc[j][2]); acc[j][3] = fmaf(xv, wa.w, acc[j][3]);
      acc[j][4] = fmaf(xv, wb.x, acc[j][4]); acc[j][5] = fmaf(xv, wb.y, acc[j][5]);
      acc[j][6] = fmaf(xv, wb.z, acc[j][6]); acc[j][7] = fmaf(xv, wb.w, acc[j][7]);
    }
  }
  const int row = row0 + r;
  const int b = row >> 11, s = row & 2047;
  // 1/sqrt(8) * log2(e): attention scores land in exp2 domain
  const float qscale = 0.35355339059327373f * 1.4426950408889634f;
  #pragma unroll
  for (int j = 0; j < 3; ++j) {
    int c = wg * 3 + j;
    int m = c >> 3, h = c & 7;
    float sc = (m == 0) ? qscale : 1.f;
    float* dst = ((m == 0) ? Qo : ((m == 1) ? Ko : Vo)) + (((size_t)(h * NB + b) * SS) + s) * DD;
    float4 o0 = make_float4(acc[j][0] * sc, acc[j][1] * sc, acc[j][2] * sc, acc[j][3] * sc);
    float4 o1 = make_float4(acc[j][4] * sc, acc[j][5] * sc, acc[j][6] * sc, acc[j][7] * sc);
    reinterpret_cast<float4*>(dst)[0] = o0;
    reinterpret_cast<float4*>(dst)[1] = o1;
  }
}

// ---------------- Kernel B: softmax weights + head sums ----------------
// Grid: 1024 blocks = 32 (h,b) x 32 row-tiles of 64 rows. 256 threads = 4 waves.
// All dot products via v_pk_fma_f32 (packed 2xf32); exponentials via raw
// v_exp_f32 (Q pre-scaled by log2e, nls = -log2(rowsum) folded into FMA seed).
// Phase 1 (lane = row): per-wave-private LDS K chunks, broadcast k_t reads.
// Phase 2 (lane = 4 t): float4 weight stores, colsum trick for the head sums.
__global__ __launch_bounds__(256, 4) void attn_kernel(
    const float* __restrict__ Qg, const float* __restrict__ Kg, const float* __restrict__ Vg,
    float* __restrict__ wOut, float* __restrict__ hsum2) {
  __shared__ float4 klds[4 * 512];   // 4 waves x 256 t x 2 float4 = 32 KB (wave-private)
  __shared__ float4 qlds[128];       // 64 rows x 8 floats = 2 KB (for phase 2)
  __shared__ float psum[4][64];
  __shared__ float nls_s[64];        // -log2(rowsum)
  __shared__ float hred[4][8];
  const int tid = threadIdx.x;
  const int lane = tid & 63;
  const int w = tid >> 6;
  const int bx = blockIdx.x;
  const int hb = bx >> 5;   // h*4+b
  const int rt = bx & 31;
  const int r0 = rt * 64;
  const float* Kbase = Kg + (size_t)hb * SS * DD;
  const float* Vbase = Vg + (size_t)hb * SS * DD;
  const float4* K4 = reinterpret_cast<const float4*>(Kbase);
  const float4* Q4 = reinterpret_cast<const float4*>(Qg + (size_t)hb * SS * DD + (size_t)r0 * DD);
  float* wBase = wOut + (size_t)hb * SS * SS + (size_t)r0 * SS;

  // stage Q tile for phase 2 (consumed after the psum barrier)
  if (tid < 128) qlds[tid] = Q4[tid];

  // ---- Phase 1: row sums. lane = row r0+lane; wave w covers t in [w*512, w*512+512). ----
  float4 qa = Q4[lane * 2], qb = Q4[lane * 2 + 1];
  f32x2 q01, q23, q45, q67;
  q01.x = qa.x; q01.y = qa.y; q23.x = qa.z; q23.y = qa.w;
  q45.x = qb.x; q45.y = qb.y; q67.x = qb.z; q67.y = qb.w;
  float rs0 = 0.f, rs1 = 0.f;
  float4* kw = klds + w * 512;   // this wave's private 8 KB buffer
  for (int cc = 0; cc < 2; ++cc) {
    const int t0 = (w * 2 + cc) * 256;
    // stage 256 K rows (8 KB) cooperatively within the wave; no block barrier needed
    #pragma unroll
    for (int i = 0; i < 8; ++i) kw[lane + 64 * i] = K4[(size_t)t0 * 2 + lane + 64 * i];
    // broadcast reads with register prefetch (4 t per step)
    float4 a0 = kw[0], b0 = kw[1], a1 = kw[2], b1 = kw[3];
    float4 a2 = kw[4], b2 = kw[5], a3 = kw[6], b3 = kw[7];
    for (int tt = 0; tt < 256; tt += 4) {
      const int tn = (tt + 4 < 256) ? (tt + 4) : 0;  // wrap = dummy prefetch
      float4 na0 = kw[2 * tn],     nb0 = kw[2 * tn + 1];
      float4 na1 = kw[2 * tn + 2], nb1 = kw[2 * tn + 3];
      float4 na2 = kw[2 * tn + 4], nb2 = kw[2 * tn + 5];
      float4 na3 = kw[2 * tn + 6], nb3 = kw[2 * tn + 7];
      f32x2 d0 = q01 * lo2(a0);
      d0 = pkfma(q23, hi2(a0), d0); d0 = pkfma(q45, lo2(b0), d0); d0 = pkfma(q67, hi2(b0), d0);
      f32x2 d1 = q01 * lo2(a1);
      d1 = pkfma(q23, hi2(a1), d1); d1 = pkfma(q45, lo2(b1), d1); d1 = pkfma(q67, hi2(b1), d1);
      f32x2 d2 = q01 * lo2(a2);
      d2 = pkfma(q23, hi2(a2), d2); d2 = pkfma(q45, lo2(b2), d2); d2 = pkfma(q67, hi2(b2), d2);
      f32x2 d3 = q01 * lo2(a3);
      d3 = pkfma(q23, hi2(a3), d3); d3 = pkfma(q45, lo2(b3), d3); d3 = pkfma(q67, hi2(b3), d3);
      rs0 += fastexp2(d0.x + d0.y) + fastexp2(d1.x + d1.y);
      rs1 += fastexp2(d2.x + d2.y) + fastexp2(d3.x + d3.y);
      a0 = na0; b0 = nb0; a1 = na1; b1 = nb1;
      a2 = na2; b2 = nb2; a3 = na3; b3 = nb3;
    }
  }
  psum[w][lane] = rs0 + rs1;
  __syncthreads();
  if (tid < 64)
    nls_s[tid] = -log2f(psum[0][tid] + psum[1][tid] + psum[2][tid] + psum[3][tid]);
  __syncthreads();

  // ---- Phase 2: lane owns t = tbase + 4*lane + {0..3}; float4 weight stores. ----
  float A[8] = {0.f, 0.f, 0.f, 0.f, 0.f, 0.f, 0.f, 0.f};
  for (int ci = 0; ci < 2; ++ci) {
    const int c = w * 2 + ci;          // 0..7
    const int tbase = c * 256;
    const int tl = tbase + 4 * lane;   // first t for this lane
    const float4* kp = reinterpret_cast<const float4*>(Kbase + (size_t)tl * DD);
    float4 k0a = kp[0], k0b = kp[1], k1a = kp[2], k1b = kp[3];
    float4 k2a = kp[4], k2b = kp[5], k3a = kp[6], k3b = kp[7];
    float4 qa2 = qlds[0], qb2 = qlds[1];
    float nl = nls_s[0];
    float cs0 = 0.f, cs1 = 0.f, cs2 = 0.f, cs3 = 0.f;
    for (int r = 0; r < 64; ++r) {
      const int rn = (r < 63) ? (r + 1) : 63;
      float4 na = qlds[rn * 2], nb = qlds[rn * 2 + 1];  // prefetch next row's q
      float nln = nls_s[rn];
      f32x2 p01, p23, p45, p67, seed;
      p01.x = qa2.x; p01.y = qa2.y; p23.x = qa2.z; p23.y = qa2.w;
      p45.x = qb2.x; p45.y = qb2.y; p67.x = qb2.z; p67.y = qb2.w;
      seed.x = nl; seed.y = 0.f;
      f32x2 d0 = pkfma(p01, lo2(k0a), seed);
      d0 = pkfma(p23, hi2(k0a), d0); d0 = pkfma(p45, lo2(k0b), d0); d0 = pkfma(p67, hi2(k0b), d0);
      f32x2 d1 = pkfma(p01, lo2(k1a), seed);
      d1 = pkfma(p23, hi2(k1a), d1); d1 = pkfma(p45, lo2(k1b), d1); d1 = pkfma(p67, hi2(k1b), d1);
      f32x2 d2 = pkfma(p01, lo2(k2a), seed);
      d2 = pkfma(p23, hi2(k2a), d2); d2 = pkfma(p45, lo2(k2b), d2); d2 = pkfma(p67, hi2(k2b), d2);
      f32x2 d3 = pkfma(p01, lo2(k3a), seed);
      d3 = pkfma(p23, hi2(k3a), d3); d3 = pkfma(p45, lo2(k3b), d3); d3 = pkfma(p67, hi2(k3b), d3);
      float p0 = fastexp2(d0.x + d0.y);
      float p1 = fastexp2(d1.x + d1.y);
      float p2 = fastexp2(d2.x + d2.y);
      float p3 = fastexp2(d3.x + d3.y);
      reinterpret_cast<float4*>(wBase + (size_t)r * SS + tl)[0] = make_float4(p0, p1, p2, p3);
      cs0 += p0; cs1 += p1; cs2 += p2; cs3 += p3;
      qa2 = na; qb2 = nb; nl = nln;
    }
    // apply V once per chunk: A[d] += colsum(t) * V[t][d]
    const float4* vp = reinterpret_cast<const float4*>(Vbase + (size_t)tl * DD);
    float4 v0a = vp[0], v0b = vp[1], v1a = vp[2], v1b = vp[3];
    float4 v2a = vp[4], v2b = vp[5], v3a = vp[6], v3b = vp[7];
    A[0] = fmaf(cs0, v0a.x, A[0]); A[0] = fmaf(cs1, v1a.x, A[0]);
    A[0] = fmaf(cs2, v2a.x, A[0]); A[0] = fmaf(cs3, v3a.x, A[0]);
    A[1] = fmaf(cs0, v0a.y, A[1]); A[1] = fmaf(cs1, v1a.y, A[1]);
    A[1] = fmaf(cs2, v2a.y, A[1]); A[1] = fmaf(cs3, v3a.y, A[1]);
    A[2] = fmaf(cs0, v0a.z, A[2]); A[2] = fmaf(cs1, v1a.z, A[2]);
    A[2] = fmaf(cs2, v2a.z, A[2]); A[2] = fmaf(cs3, v3a.z, A[2]);
    A[3] = fmaf(cs0, v0a.w, A[3]); A[3] = fmaf(cs1, v1a.w, A[3]);
    A[3] = fmaf(cs2, v2a.w, A[3]); A[3] = fmaf(cs3, v3a.w, A[3]);
    A[4] = fmaf(cs0, v0b.x, A[4]); A[4] = fmaf(cs1, v1b.x, A[4]);
    A[4] = fmaf(cs2, v2b.x, A[4]); A[4] = fmaf(cs3, v3b.x, A[4]);
    A[5] = fmaf(cs0, v0b.y, A[5]); A[5] = fmaf(cs1, v1b.y, A[5]);
    A[5] = fmaf(cs2, v2b.y, A[5]); A[5] = fmaf(cs3, v3b.y, A[5]);
    A[6] = fmaf(cs0, v0b.z, A[6]); A[6] = fmaf(cs1, v1b.z, A[6]);
    A[6] = fmaf(cs2, v2b.z, A[6]); A[6] = fmaf(cs3, v3b.z, A[6]);
    A[7] = fmaf(cs0, v0b.w, A[7]); A[7] = fmaf(cs1, v1b.w, A[7]);
    A[7] = fmaf(cs2, v2b.w, A[7]); A[7] = fmaf(cs3, v3b.w, A[7]);
  }

  // block-level reduce of A[d] -> hsum2[bx][d]
  #pragma unroll
  for (int d = 0; d < 8; ++d) {
    float t = wave_sum64(A[d]);
    if (lane == 63) hred[w][d] = t;
  }
  __syncthreads();
  if (tid < 8) {
    float t = hred[0][tid] + hred[1][tid] + hred[2][tid] + hred[3][tid];
    hsum2[(size_t)bx * 8 + tid] = t;
  }
}

// ---------------- Kernel C: combine head sums + output projection ----------------
__global__ __launch_bounds__(256) void out_kernel(
    const float* __restrict__ hsum2, const float* __restrict__ Wo,
    float* __restrict__ out) {
  __shared__ float ch[256];  // [hb][d] = [h*4+b]*8 + d
  const int tid = threadIdx.x;
  {
    int hb = tid >> 3, d = tid & 7;
    float s = 0.f;
    for (int rtile = 0; rtile < 32; ++rtile) s += hsum2[(size_t)(hb * 32 + rtile) * 8 + d];
    ch[tid] = s;
  }
  __syncthreads();
  const int b = tid >> 6, f = tid & 63;
  float acc = 0.f;
  for (int h = 0; h < 8; ++h) {
    #pragma unroll
    for (int d = 0; d < 8; ++d) {
      // concat[b][h*8+d] @ Wo[h*8+d][f]
      acc = fmaf(ch[(h * 4 + b) * 8 + d], Wo[(h * 8 + d) * 64 + f], acc);
    }
  }
  out[b * 64 + f] = acc;
}

extern "C" void kernel_launch(void* const* d_in, const int* in_sizes, int n_in,
                              void* d_out, int out_size, void* d_ws, size_t ws_size,
                              hipStream_t stream) {
  const float* x  = (const float*)d_in[0];
  const float* Wq = (const float*)d_in[1];
  const float* Wk = (const float*)d_in[2];
  const float* Wv = (const float*)d_in[3];
  const float* Wo = (const float*)d_in[4];
  float* out = (float*)d_out;           // [4,64] = 256 floats
  float* wts = out + 256;               // weights [8,4,2048,2048]
  float* ws = (float*)d_ws;
  float* Q = ws;
  float* K = ws + QKV_SZ;
  float* V = ws + 2 * (size_t)QKV_SZ;
  float* hs = ws + 3 * (size_t)QKV_SZ;  // [1024][8]

  qkv_kernel<<<dim3(128, 2), 256, 0, stream>>>(x, Wq, Wk, Wv, Q, K, V);
  attn_kernel<<<1024, 256, 0, stream>>>(Q, K, V, wts, hs);
  out_kernel<<<1, 256, 0, stream>>>(hs, Wo, out);
}